// Round 6
// baseline (284.292 us; speedup 1.0000x reference)
//
#include <hip/hip_runtime.h>

// LinearAttention MI355X: B=2, C=96, N=131072 (x stored [B,C,N]), 8 heads x hd=12.
// TLP-first split: 64-token tiles, 1 tile/block, 4096 blocks, small LDS, VGPR<=128
// -> 4+ blocks/CU (50% occupancy) to hide load/barrier latency (r5 showed ILP
// prefetch was a null: pA 75us at 20% occ, all pipes idle).
//   k1 : weights fp32->fp16 + zero part
//   pA : k/v GEMMs -> ke,vl LDS (24.5KB) -> context+S -> atomics     (1 barrier)
//   kB : fold part+Wproj -> Mt fp16 (tiny)
//   pC : q GEMM -> qs LDS (16KB) -> softmax -> out GEMM              (2 barriers)
//
// Fragment layouts (gfx950, verified learn_hip m89/m118/m120):
//   A[m=lane&15][k=quad*8+j], B[k=quad*8+j][n=lane&15], C/D row=quad*4+reg col=lane&15

typedef _Float16 half_t;
typedef _Float16 half8 __attribute__((ext_vector_type(8)));
typedef float f32x4 __attribute__((ext_vector_type(4)));

#define MFMA16 __builtin_amdgcn_mfma_f32_16x16x32_f16
#define NSH 17
#define NP 32   // partial reduction buffers

// [row][64 halves] tile (128B rows): 16B-block XOR over 8 rows
__device__ __forceinline__ int swz64(int row, int colh) {
  return (row * 128 + colh * 2) ^ ((row & 7) << 4);
}
// [row][128 halves] tile (256B rows)
__device__ __forceinline__ int swz128(int row, int colh) {
  return (row * 256 + colh * 2) ^ ((row & 7) << 4);
}

// ---------------- k1: weights fp32->fp16 + zero part ----------------
__global__ void k1(const float* __restrict__ Wq, const float* __restrict__ Wk,
                   const float* __restrict__ Wv, half_t* __restrict__ WqH,
                   half_t* __restrict__ WkH, half_t* __restrict__ WvH,
                   float* __restrict__ part) {
  const int g = blockIdx.x * 256 + threadIdx.x;   // 36*256 = 9216 exactly
  WqH[g] = (half_t)Wq[g];
  WkH[g] = (half_t)Wk[g];
  WvH[g] = (half_t)Wv[g];
  for (int i = g; i < NP * 2 * 1248; i += 9216) part[i] = 0.f;
}

// ---------------- pA: k,v GEMMs + context (64-token tile) ----------------
__global__ __launch_bounds__(256, 4)
void pA(const float* __restrict__ x, const half_t* __restrict__ WkH,
        const half_t* __restrict__ WvH, float* __restrict__ part) {
  // LDS: ke [96][64]h swz @0 (12288), vl @12288. total 24576 -> 4+ blocks/CU
  __shared__ __align__(16) char smem[24576];

  const int tid  = threadIdx.x;
  const int lane = tid & 63, l15 = lane & 15, quad = lane >> 4, wid = tid >> 6;
  const int bid  = blockIdx.x;                 // 4096 blocks = 2 b x 2048 tiles
  const int b    = bid >> 11;
  const int n0   = (bid & 2047) << 6;
  float* dst = part + (size_t)((bid & (NP - 1)) * 2 + b) * 1248;

  // ---- x tile -> registers (24 dword loads) -> fp16 B-fragments ----
  half8 bf[3];
  {
    float xv[24];
    const float* xb = x + (((size_t)(b * 96 + quad * 8)) << NSH) + n0 + wid * 16 + l15;
#pragma unroll
    for (int ks = 0; ks < 3; ++ks)
#pragma unroll
      for (int j = 0; j < 8; ++j)
        xv[ks * 8 + j] = xb[(((size_t)(ks * 32 + j)) << NSH)];
#pragma unroll
    for (int ks = 0; ks < 3; ++ks)
#pragma unroll
      for (int j = 0; j < 8; ++j)
        bf[ks][j] = (half_t)xv[ks * 8 + j];
  }

  f32x4 acc[6];
  // ---- k GEMM: D[c_out][token] ----
#pragma unroll
  for (int rt = 0; rt < 6; ++rt) acc[rt] = (f32x4){0.f, 0.f, 0.f, 0.f};
#pragma unroll
  for (int ks = 0; ks < 3; ++ks) {
    half8 af[6];
#pragma unroll
    for (int rt = 0; rt < 6; ++rt)
      af[rt] = *(const half8*)&WkH[(rt * 16 + l15) * 96 + ks * 32 + quad * 8];
#pragma unroll
    for (int rt = 0; rt < 6; ++rt)
      acc[rt] = MFMA16(af[rt], bf[ks], acc[rt], 0, 0, 0);
  }
  // exp epilogue -> ke (swizzled)
#pragma unroll
  for (int rt = 0; rt < 6; ++rt)
#pragma unroll
    for (int i = 0; i < 4; ++i) {
      int row = rt * 16 + quad * 4 + i;
      int col = wid * 16 + l15;
      *(half_t*)(smem + swz64(row, col)) = (half_t)__expf(acc[rt][i]);
    }

  // ---- v GEMM ----
#pragma unroll
  for (int rt = 0; rt < 6; ++rt) acc[rt] = (f32x4){0.f, 0.f, 0.f, 0.f};
#pragma unroll
  for (int ks = 0; ks < 3; ++ks) {
    half8 af[6];
#pragma unroll
    for (int rt = 0; rt < 6; ++rt)
      af[rt] = *(const half8*)&WvH[(rt * 16 + l15) * 96 + ks * 32 + quad * 8];
#pragma unroll
    for (int rt = 0; rt < 6; ++rt)
      acc[rt] = MFMA16(af[rt], bf[ks], acc[rt], 0, 0, 0);
  }
#pragma unroll
  for (int rt = 0; rt < 6; ++rt)
#pragma unroll
    for (int i = 0; i < 4; ++i) {
      int row = rt * 16 + quad * 4 + i;
      int col = wid * 16 + l15;
      *(half_t*)(smem + 12288 + swz64(row, col)) = (half_t)acc[rt][i];
    }
  __syncthreads();   // the only barrier

  // ---- context MFMA over tokens: wave wid handles heads 2w, 2w+1 ----
#pragma unroll
  for (int hh = 0; hh < 2; ++hh) {
    const int h = wid * 2 + hh;
    int row = h * 12 + l15; row = row > 95 ? 95 : row;   // clamp, m>=12 discarded
    f32x4 c = (f32x4){0.f, 0.f, 0.f, 0.f};
#pragma unroll
    for (int ks = 0; ks < 2; ++ks) {
      const int off = swz64(row, ks * 32 + quad * 8);
      half8 a  = *(const half8*)(smem + off);
      half8 bv = *(const half8*)(smem + 12288 + off);
      c = MFMA16(a, bv, c, 0, 0, 0);
    }
#pragma unroll
    for (int i = 0; i < 4; ++i) {
      int d = quad * 4 + i, e = l15;
      if (d < 12 && e < 12) atomicAdd(&dst[h * 144 + d * 12 + e], c[i]);
    }
  }
  // ---- S row sums (threads 0..95) ----
  if (tid < 96) {
    float s = 0.f;
#pragma unroll
    for (int j = 0; j < 8; ++j) {
      half8 v = *(const half8*)(smem + swz64(tid, j * 8));
#pragma unroll
      for (int e = 0; e < 8; ++e) s += (float)v[e];
    }
    atomicAdd(&dst[1152 + tid], s);
  }
}

// ---------------- kB: fold part + Wproj -> Mt fp16 ----------------
__global__ void kB(const float* __restrict__ part, const float* __restrict__ Wproj,
                   half_t* __restrict__ Mt) {
  const int g = blockIdx.x * 256 + threadIdx.x;   // 72*256 = 18432 = 2*96*96
  const int b = g / (96 * 96);
  const int rem = g % (96 * 96);
  const int o = rem / 96;
  const int r = rem % 96;        // r = h*12+d
  const int h = r / 12, d = r % 12;
  float s = 0.f;
#pragma unroll
  for (int p = 0; p < NP; ++p) s += part[(size_t)(p * 2 + b) * 1248 + 1152 + r];
  float acc = 0.f;
#pragma unroll
  for (int e = 0; e < 12; ++e) {
    float ce = 0.f;
#pragma unroll
    for (int p = 0; p < NP; ++p)
      ce += part[(size_t)(p * 2 + b) * 1248 + h * 144 + d * 12 + e];
    acc = fmaf(ce, Wproj[o * 96 + h * 12 + e], acc);
  }
  Mt[(size_t)(b * 96 + o) * 96 + r] = (half_t)(acc / s);
}

// ---------------- pC: q GEMM + softmax + out GEMM (64-token tile) ----------------
__global__ __launch_bounds__(256, 4)
void pC(const float* __restrict__ x, const half_t* __restrict__ WqH,
        const half_t* __restrict__ Mt, float* __restrict__ out) {
  // LDS: qs [64 tokens][128 ch]h swz = 16384 -> 4+ blocks/CU (wave-capped)
  __shared__ __align__(16) char smem[16384];

  const int tid  = threadIdx.x;
  const int lane = tid & 63, l15 = lane & 15, quad = lane >> 4, wid = tid >> 6;
  const int bid  = blockIdx.x;
  const int b    = bid >> 11;
  const int n0   = (bid & 2047) << 6;

  half8 bf[3];
  {
    float xv[24];
    const float* xb = x + (((size_t)(b * 96 + quad * 8)) << NSH) + n0 + wid * 16 + l15;
#pragma unroll
    for (int ks = 0; ks < 3; ++ks)
#pragma unroll
      for (int j = 0; j < 8; ++j)
        xv[ks * 8 + j] = xb[(((size_t)(ks * 32 + j)) << NSH)];
#pragma unroll
    for (int ks = 0; ks < 3; ++ks)
#pragma unroll
      for (int j = 0; j < 8; ++j)
        bf[ks][j] = (half_t)xv[ks * 8 + j];
  }

  f32x4 acc[6];
  // ---- q GEMM ----
#pragma unroll
  for (int rt = 0; rt < 6; ++rt) acc[rt] = (f32x4){0.f, 0.f, 0.f, 0.f};
#pragma unroll
  for (int ks = 0; ks < 3; ++ks) {
    half8 af[6];
#pragma unroll
    for (int rt = 0; rt < 6; ++rt)
      af[rt] = *(const half8*)&WqH[(rt * 16 + l15) * 96 + ks * 32 + quad * 8];
#pragma unroll
    for (int rt = 0; rt < 6; ++rt)
      acc[rt] = MFMA16(af[rt], bf[ks], acc[rt], 0, 0, 0);
  }
  // q logits transposed into qs[token][ch] (swizzled)
#pragma unroll
  for (int rt = 0; rt < 6; ++rt)
#pragma unroll
    for (int i = 0; i < 4; ++i) {
      int ch  = rt * 16 + quad * 4 + i;
      int tok = wid * 16 + l15;
      *(half_t*)(smem + swz128(tok, ch)) = (half_t)acc[rt][i];
    }
  __syncthreads();

  // softmax over head dim: thread owns (token n = tid&63, head-group hg of 2 heads)
  {
    const int n = tid & 63, hg = tid >> 6;       // hg 0..3 -> channels hg*24..+23
    float q[24];
#pragma unroll
    for (int j = 0; j < 3; ++j) {
      half8 v = *(const half8*)(smem + swz128(n, hg * 24 + j * 8));
#pragma unroll
      for (int e = 0; e < 8; ++e) q[j * 8 + e] = (float)v[e];
    }
#pragma unroll
    for (int hh = 0; hh < 2; ++hh) {
      float* ql = q + hh * 12;
      float m = ql[0];
#pragma unroll
      for (int j = 1; j < 12; ++j) m = fmaxf(m, ql[j]);
      float s = 0.f;
#pragma unroll
      for (int j = 0; j < 12; ++j) { ql[j] = __expf(ql[j] - m); s += ql[j]; }
      const float inv = 1.0f / s;
#pragma unroll
      for (int j = 0; j < 12; ++j) ql[j] *= inv;
    }
#pragma unroll
    for (int j = 0; j < 3; ++j) {
      half8 w;
#pragma unroll
      for (int e = 0; e < 8; ++e) w[e] = (half_t)q[j * 8 + e];
      *(half8*)(smem + swz128(n, hg * 24 + j * 8)) = w;
    }
  }
  __syncthreads();

  // ---- out GEMM: D[o][tok] = sum_r Mt[o][r]*q[r][tok]; A from global Mt (L2-hot) ----
#pragma unroll
  for (int rt = 0; rt < 6; ++rt) acc[rt] = (f32x4){0.f, 0.f, 0.f, 0.f};
#pragma unroll
  for (int ks = 0; ks < 3; ++ks) {
    half8 af[6], bq;
#pragma unroll
    for (int rt = 0; rt < 6; ++rt)
      af[rt] = *(const half8*)&Mt[(size_t)b * 9216 + (rt * 16 + l15) * 96 + ks * 32 + quad * 8];
    bq = *(const half8*)(smem + swz128(wid * 16 + l15, ks * 32 + quad * 8));
#pragma unroll
    for (int rt = 0; rt < 6; ++rt)
      acc[rt] = MFMA16(af[rt], bq, acc[rt], 0, 0, 0);
  }
#pragma unroll
  for (int rt = 0; rt < 6; ++rt)
#pragma unroll
    for (int i = 0; i < 4; ++i) {
      int row = rt * 16 + quad * 4 + i;
      int col = wid * 16 + l15;
      out[(((size_t)(b * 96 + row)) << NSH) + n0 + col] = acc[rt][i];
    }
}

extern "C" void kernel_launch(void* const* d_in, const int* in_sizes, int n_in,
                              void* d_out, int out_size, void* d_ws, size_t ws_size,
                              hipStream_t stream) {
  const float* x     = (const float*)d_in[0];
  const float* Wq    = (const float*)d_in[1];
  const float* Wk    = (const float*)d_in[2];
  const float* Wv    = (const float*)d_in[3];
  const float* Wproj = (const float*)d_in[4];
  float* out = (float*)d_out;
  float* ws  = (float*)d_ws;

  float*  part = ws;                                    // NP*2*1248 = 79872 f32
  half_t* MtH  = (half_t*)(ws + NP * 2 * 1248);         // 18432 h = 9216 f32
  half_t* WqH  = (half_t*)(ws + NP * 2 * 1248 + 9216);  // 9216 h each
  half_t* WkH  = WqH + 9216;
  half_t* WvH  = WkH + 9216;

  k1<<<36, 256, 0, stream>>>(Wq, Wk, Wv, WqH, WkH, WvH, part);
  pA<<<4096, 256, 0, stream>>>(x, WkH, WvH, part);
  kB<<<72, 256, 0, stream>>>(part, Wproj, MtH);
  pC<<<4096, 256, 0, stream>>>(x, WqH, MtH, out);
}

// Round 9
// 250.105 us; speedup vs baseline: 1.1367x; 1.1367x over previous
//
#include <hip/hip_runtime.h>

// LinearAttention MI355X: B=2, C=96, N=131072 (x stored [B,C,N]), 8 heads x hd=12.
// Discriminating round: qt path deleted (r7/r8 container failures are either infra
// or qt-correlated; every kernel below is measured lineage that ran on hardware).
//   k1  : weights fp32->fp16 + zero part          (r5 lineage, ran)
//   pA  : x -> k/v GEMMs -> ke,vl LDS -> ctx+S    (r1 p1 structure, 75us measured)
//   kB  : fold part+Wproj -> Mt fp16              (r0 lineage, ran)
//   pC_x: x -> q GEMM -> softmax -> out GEMM      (r1 p3 structure, ~60us measured)
//
// Fragment layouts (gfx950, verified learn_hip m89/m118/m120):
//   A[m=lane&15][k=quad*8+j], B[k=quad*8+j][n=lane&15], C/D row=quad*4+reg col=lane&15

typedef _Float16 half_t;
typedef _Float16 half8 __attribute__((ext_vector_type(8)));
typedef float f32x4 __attribute__((ext_vector_type(4)));

#define MFMA16 __builtin_amdgcn_mfma_f32_16x16x32_f16
#define NSH 17
#define NP 16   // partial reduction buffers

// swizzled byte offset in a [row][128 halves] LDS tile (16B-block XOR keeps b128 alignment)
__device__ __forceinline__ int swz(int row, int colh) {
  return (row * 256 + colh * 2) ^ ((row & 7) << 4);
}

// ---------------- k1: weights fp32->fp16 + zero part ----------------
__global__ void k1(const float* __restrict__ Wq, const float* __restrict__ Wk,
                   const float* __restrict__ Wv, half_t* __restrict__ WqH,
                   half_t* __restrict__ WkH, half_t* __restrict__ WvH,
                   float* __restrict__ part) {
  const int g = blockIdx.x * 256 + threadIdx.x;   // 36*256 = 9216 exactly
  WqH[g] = (half_t)Wq[g];
  WkH[g] = (half_t)Wk[g];
  WvH[g] = (half_t)Wv[g];
  for (int i = g; i < NP * 2 * 1248; i += 9216) part[i] = 0.f;
}

// ---------------- pA: k,v GEMMs + context (128-token tile) ----------------
__global__ __launch_bounds__(256, 2)
void pA(const float* __restrict__ x, const half_t* __restrict__ WkH,
        const half_t* __restrict__ WvH, float* __restrict__ part) {
  // LDS: ke [96][128]h swz @0 (24576), vl @24576. total 49152
  __shared__ __align__(16) char smem[49152];

  const int tid  = threadIdx.x;
  const int lane = tid & 63, l15 = lane & 15, quad = lane >> 4, wid = tid >> 6;
  const int bid  = blockIdx.x;                 // 2048 blocks = 2 b x 1024 tiles
  const int b    = bid >> 10;
  const int n0   = (bid & 1023) << 7;
  float* dst = part + (size_t)((bid & (NP - 1)) * 2 + b) * 1248;

  // ---- x tile -> registers (48 dword loads) -> fp16 B-fragments ----
  half8 bf[3][2];
  {
    float xv[48];
    const float* xb = x + (((size_t)(b * 96 + quad * 8)) << NSH) + n0 + wid * 32 + l15;
#pragma unroll
    for (int ks = 0; ks < 3; ++ks)
#pragma unroll
      for (int j = 0; j < 8; ++j)
#pragma unroll
        for (int ct = 0; ct < 2; ++ct)
          xv[(ks * 8 + j) * 2 + ct] = xb[(((size_t)(ks * 32 + j)) << NSH) + ct * 16];
#pragma unroll
    for (int ks = 0; ks < 3; ++ks)
#pragma unroll
      for (int ct = 0; ct < 2; ++ct)
#pragma unroll
        for (int j = 0; j < 8; ++j)
          bf[ks][ct][j] = (half_t)xv[(ks * 8 + j) * 2 + ct];
  }

  f32x4 acc[6][2];
  // ---- k GEMM: D[c_out][token] ----
#pragma unroll
  for (int rt = 0; rt < 6; ++rt)
#pragma unroll
    for (int ct = 0; ct < 2; ++ct) acc[rt][ct] = (f32x4){0.f, 0.f, 0.f, 0.f};
#pragma unroll
  for (int ks = 0; ks < 3; ++ks) {
    half8 af[6];
#pragma unroll
    for (int rt = 0; rt < 6; ++rt)
      af[rt] = *(const half8*)&WkH[(rt * 16 + l15) * 96 + ks * 32 + quad * 8];
#pragma unroll
    for (int rt = 0; rt < 6; ++rt)
#pragma unroll
      for (int ct = 0; ct < 2; ++ct)
        acc[rt][ct] = MFMA16(af[rt], bf[ks][ct], acc[rt][ct], 0, 0, 0);
  }
  // exp epilogue -> ke (swizzled)
#pragma unroll
  for (int rt = 0; rt < 6; ++rt)
#pragma unroll
    for (int ct = 0; ct < 2; ++ct)
#pragma unroll
      for (int i = 0; i < 4; ++i) {
        int row = rt * 16 + quad * 4 + i;
        int col = (wid * 2 + ct) * 16 + l15;
        *(half_t*)(smem + swz(row, col)) = (half_t)__expf(acc[rt][ct][i]);
      }

  // ---- v GEMM ----
#pragma unroll
  for (int rt = 0; rt < 6; ++rt)
#pragma unroll
    for (int ct = 0; ct < 2; ++ct) acc[rt][ct] = (f32x4){0.f, 0.f, 0.f, 0.f};
#pragma unroll
  for (int ks = 0; ks < 3; ++ks) {
    half8 af[6];
#pragma unroll
    for (int rt = 0; rt < 6; ++rt)
      af[rt] = *(const half8*)&WvH[(rt * 16 + l15) * 96 + ks * 32 + quad * 8];
#pragma unroll
    for (int rt = 0; rt < 6; ++rt)
#pragma unroll
      for (int ct = 0; ct < 2; ++ct)
        acc[rt][ct] = MFMA16(af[rt], bf[ks][ct], acc[rt][ct], 0, 0, 0);
  }
#pragma unroll
  for (int rt = 0; rt < 6; ++rt)
#pragma unroll
    for (int ct = 0; ct < 2; ++ct)
#pragma unroll
      for (int i = 0; i < 4; ++i) {
        int row = rt * 16 + quad * 4 + i;
        int col = (wid * 2 + ct) * 16 + l15;
        *(half_t*)(smem + 24576 + swz(row, col)) = (half_t)acc[rt][ct][i];
      }
  __syncthreads();

  // ---- context MFMA over tokens: wave wid handles heads 2w, 2w+1 ----
#pragma unroll
  for (int hh = 0; hh < 2; ++hh) {
    const int h = wid * 2 + hh;
    int row = h * 12 + l15; row = row > 95 ? 95 : row;   // clamp, m>=12 discarded
    f32x4 c = (f32x4){0.f, 0.f, 0.f, 0.f};
#pragma unroll
    for (int ks = 0; ks < 4; ++ks) {
      const int off = swz(row, ks * 32 + quad * 8);
      half8 a  = *(const half8*)(smem + off);
      half8 bv = *(const half8*)(smem + 24576 + off);
      c = MFMA16(a, bv, c, 0, 0, 0);
    }
#pragma unroll
    for (int i = 0; i < 4; ++i) {
      int d = quad * 4 + i, e = l15;
      if (d < 12 && e < 12) atomicAdd(&dst[h * 144 + d * 12 + e], c[i]);
    }
  }
  // ---- S row sums (threads 0..95) ----
  if (tid < 96) {
    float s = 0.f;
#pragma unroll
    for (int j = 0; j < 16; ++j) {
      half8 v = *(const half8*)(smem + swz(tid, j * 8));
#pragma unroll
      for (int e = 0; e < 8; ++e) s += (float)v[e];
    }
    atomicAdd(&dst[1152 + tid], s);
  }
}

// ---------------- kB: fold part + Wproj -> Mt fp16 ----------------
__global__ void kB(const float* __restrict__ part, const float* __restrict__ Wproj,
                   half_t* __restrict__ Mt) {
  const int g = blockIdx.x * 256 + threadIdx.x;   // 72*256 = 18432 = 2*96*96
  const int b = g / (96 * 96);
  const int rem = g % (96 * 96);
  const int o = rem / 96;
  const int r = rem % 96;        // r = h*12+d
  const int h = r / 12, d = r % 12;
  float s = 0.f;
#pragma unroll
  for (int p = 0; p < NP; ++p) s += part[(size_t)(p * 2 + b) * 1248 + 1152 + r];
  float acc = 0.f;
#pragma unroll
  for (int e = 0; e < 12; ++e) {
    float ce = 0.f;
#pragma unroll
    for (int p = 0; p < NP; ++p)
      ce += part[(size_t)(p * 2 + b) * 1248 + h * 144 + d * 12 + e];
    acc = fmaf(ce, Wproj[o * 96 + h * 12 + e], acc);
  }
  Mt[(size_t)(b * 96 + o) * 96 + r] = (half_t)(acc / s);
}

// ------- pC_x: x -> q GEMM -> softmax -> out GEMM (r1 p3 structure) -------
__global__ __launch_bounds__(256, 2)
void pC_x(const float* __restrict__ x, const half_t* __restrict__ WqH,
          const half_t* __restrict__ Mt, float* __restrict__ out) {
  __shared__ __align__(16) char smem[32768];   // qs [128][128]h swz

  const int tid  = threadIdx.x;
  const int lane = tid & 63, l15 = lane & 15, quad = lane >> 4, wid = tid >> 6;
  const int bid  = blockIdx.x;
  const int b    = bid >> 10;
  const int n0   = (bid & 1023) << 7;

  half8 bf[3][2];
  {
    float xv[48];
    const float* xb = x + (((size_t)(b * 96 + quad * 8)) << NSH) + n0 + wid * 32 + l15;
#pragma unroll
    for (int ks = 0; ks < 3; ++ks)
#pragma unroll
      for (int j = 0; j < 8; ++j)
#pragma unroll
        for (int ct = 0; ct < 2; ++ct)
          xv[(ks * 8 + j) * 2 + ct] = xb[(((size_t)(ks * 32 + j)) << NSH) + ct * 16];
#pragma unroll
    for (int ks = 0; ks < 3; ++ks)
#pragma unroll
      for (int ct = 0; ct < 2; ++ct)
#pragma unroll
        for (int j = 0; j < 8; ++j)
          bf[ks][ct][j] = (half_t)xv[(ks * 8 + j) * 2 + ct];
  }

  f32x4 acc[6][2];
  // ---- q GEMM ----
#pragma unroll
  for (int rt = 0; rt < 6; ++rt)
#pragma unroll
    for (int ct = 0; ct < 2; ++ct) acc[rt][ct] = (f32x4){0.f, 0.f, 0.f, 0.f};
#pragma unroll
  for (int ks = 0; ks < 3; ++ks) {
    half8 af[6];
#pragma unroll
    for (int rt = 0; rt < 6; ++rt)
      af[rt] = *(const half8*)&WqH[(rt * 16 + l15) * 96 + ks * 32 + quad * 8];
#pragma unroll
    for (int rt = 0; rt < 6; ++rt)
#pragma unroll
      for (int ct = 0; ct < 2; ++ct)
        acc[rt][ct] = MFMA16(af[rt], bf[ks][ct], acc[rt][ct], 0, 0, 0);
  }
  // q logits transposed into qs[token][ch] (swizzled)
#pragma unroll
  for (int rt = 0; rt < 6; ++rt)
#pragma unroll
    for (int ct = 0; ct < 2; ++ct)
#pragma unroll
      for (int i = 0; i < 4; ++i) {
        int ch  = rt * 16 + quad * 4 + i;
        int tok = (wid * 2 + ct) * 16 + l15;
        *(half_t*)(smem + swz(tok, ch)) = (half_t)acc[rt][ct][i];
      }
  __syncthreads();

  // ---- softmax over head dim: thread owns (token n, head-group hg of 4 heads) ----
  {
    const int n = tid & 127, hg = tid >> 7;
    float q[48];
#pragma unroll
    for (int j = 0; j < 6; ++j) {
      half8 v = *(const half8*)(smem + swz(n, hg * 48 + j * 8));
#pragma unroll
      for (int e = 0; e < 8; ++e) q[j * 8 + e] = (float)v[e];
    }
#pragma unroll
    for (int hh = 0; hh < 4; ++hh) {
      float* ql = q + hh * 12;
      float m = ql[0];
#pragma unroll
      for (int j = 1; j < 12; ++j) m = fmaxf(m, ql[j]);
      float s = 0.f;
#pragma unroll
      for (int j = 0; j < 12; ++j) { ql[j] = __expf(ql[j] - m); s += ql[j]; }
      const float inv = 1.0f / s;
#pragma unroll
      for (int j = 0; j < 12; ++j) ql[j] *= inv;
    }
#pragma unroll
    for (int j = 0; j < 6; ++j) {
      half8 w;
#pragma unroll
      for (int e = 0; e < 8; ++e) w[e] = (half_t)q[j * 8 + e];
      *(half8*)(smem + swz(n, hg * 48 + j * 8)) = w;
    }
  }
  __syncthreads();

  // ---- out GEMM: D[o][tok] = sum_r Mt[o][r]*q[r][tok]; A = fp16 Mt (L1-hot) ----
#pragma unroll
  for (int rt = 0; rt < 6; ++rt)
#pragma unroll
    for (int ct = 0; ct < 2; ++ct) acc[rt][ct] = (f32x4){0.f, 0.f, 0.f, 0.f};
#pragma unroll
  for (int ks = 0; ks < 3; ++ks) {
    half8 af[6], bq[2];
#pragma unroll
    for (int rt = 0; rt < 6; ++rt)
      af[rt] = *(const half8*)&Mt[(size_t)b * 9216 + (rt * 16 + l15) * 96 + ks * 32 + quad * 8];
#pragma unroll
    for (int ct = 0; ct < 2; ++ct)
      bq[ct] = *(const half8*)(smem + swz((wid * 2 + ct) * 16 + l15, ks * 32 + quad * 8));
#pragma unroll
    for (int rt = 0; rt < 6; ++rt)
#pragma unroll
      for (int ct = 0; ct < 2; ++ct)
        acc[rt][ct] = MFMA16(af[rt], bq[ct], acc[rt][ct], 0, 0, 0);
  }
#pragma unroll
  for (int rt = 0; rt < 6; ++rt)
#pragma unroll
    for (int ct = 0; ct < 2; ++ct)
#pragma unroll
      for (int i = 0; i < 4; ++i) {
        int row = rt * 16 + quad * 4 + i;
        int col = (wid * 2 + ct) * 16 + l15;
        out[(((size_t)(b * 96 + row)) << NSH) + n0 + col] = acc[rt][ct][i];
      }
}

extern "C" void kernel_launch(void* const* d_in, const int* in_sizes, int n_in,
                              void* d_out, int out_size, void* d_ws, size_t ws_size,
                              hipStream_t stream) {
  const float* x     = (const float*)d_in[0];
  const float* Wq    = (const float*)d_in[1];
  const float* Wk    = (const float*)d_in[2];
  const float* Wv    = (const float*)d_in[3];
  const float* Wproj = (const float*)d_in[4];
  float* out = (float*)d_out;
  float* ws  = (float*)d_ws;

  float*  part = ws;                                    // NP*2*1248 = 39936 f32
  half_t* MtH  = (half_t*)(ws + NP * 2 * 1248);         // 18432 h = 9216 f32
  half_t* WqH  = (half_t*)(ws + NP * 2 * 1248 + 9216);  // 9216 h each (4608 f32)
  half_t* WkH  = WqH + 9216;
  half_t* WvH  = WkH + 9216;

  k1<<<36, 256, 0, stream>>>(Wq, Wk, Wv, WqH, WkH, WvH, part);
  pA<<<2048, 256, 0, stream>>>(x, WkH, WvH, part);
  kB<<<72, 256, 0, stream>>>(part, Wproj, MtH);
  pC_x<<<2048, 256, 0, stream>>>(x, WqH, MtH, out);
}